// Round 6
// baseline (143.861 us; speedup 1.0000x reference)
//
#include <hip/hip_runtime.h>

// AnalyticalBoundedLineAttractor — exact linear-regime stepping via Taylor
// recurrence:
//   z = Wx + b; m_dt = (z>0)?dt:0
//   w1 = m_dt*z - dt*x;  wk = (m_dt*(W w) - dt*w)/k;  x+ = x + sum wk
// K=3 terms; measured absmax 0.0156 vs threshold 7.7e-2.
//
// R5 post-mortem: per-element readlane broadcast + scalar fmac = >=128 VALU
// instr/matvec (measured ~520 cyc/matvec incl. W-supply overhead). This
// round halves both streams:
//   - MACs via v_pk_fma_f32 on float2 pairs (32 instr for 64 MACs),
//   - broadcast via LDS: one ds_write_b32 + 16 ds_read_b128 at wave-uniform
//     addresses (same-address reads = conflict-free broadcast; float4 result
//     = two ready v2f operands, zero unpack instructions). Single wave ->
//     DS pipe is in-order, no barriers (validated by R5 passing).
// W held as 32 x float2 per lane (row i), pinned as 64-bit "v" values so the
// pairs stay VGPR-resident and pk-consumable.

#define DT_F 0.05f
#define T_STEPS 100
#define DD 64
#define KT 3  // Taylor terms w_1..w_KT

typedef float v2f __attribute__((ext_vector_type(2)));

__device__ __forceinline__ float matvec64(const v2f (&Wp)[32], float w,
                                          float4* __restrict__ s4, int lane) {
    // Stage w for broadcast. Stride-1 write: 2 lanes/bank = free.
    reinterpret_cast<float*>(s4)[lane] = w;

    v2f acc0 = {0.f, 0.f}, acc1 = {0.f, 0.f};
    v2f acc2 = {0.f, 0.f}, acc3 = {0.f, 0.f};
#pragma unroll
    for (int r = 0; r < 16; r += 2) {
        // Wave-uniform addresses -> broadcast ds_read_b128, conflict-free.
        const float4 qa = s4[r + 0];
        const float4 qb = s4[r + 1];
        const v2f sa0 = {qa.x, qa.y}, sa1 = {qa.z, qa.w};
        const v2f sb0 = {qb.x, qb.y}, sb1 = {qb.z, qb.w};
        acc0 = __builtin_elementwise_fma(Wp[2 * r + 0], sa0, acc0);
        acc1 = __builtin_elementwise_fma(Wp[2 * r + 1], sa1, acc1);
        acc2 = __builtin_elementwise_fma(Wp[2 * r + 2], sb0, acc2);
        acc3 = __builtin_elementwise_fma(Wp[2 * r + 3], sb1, acc3);
    }
    const v2f ps = (acc0 + acc1) + (acc2 + acc3);
    return ps.x + ps.y;
}

__global__ __launch_bounds__(64, 1)
__attribute__((amdgpu_waves_per_eu(1, 1)))
void abla_kernel(const float* __restrict__ x0,
                 const float* __restrict__ W,
                 const float* __restrict__ bvec,
                 float* __restrict__ out) {
    const int batch = blockIdx.x;
    const int lane = threadIdx.x;

    __shared__ float4 sbuf[2][DD / 4];  // broadcast double buffer (512 B)

    // Lane i caches row i of W as 32 float2 pairs (64 VGPRs), pinned as
    // 64-bit values so they stay pk_fma-consumable register pairs.
    v2f Wp[32];
#pragma unroll
    for (int j = 0; j < DD; j += 4) {
        const float4 w4 = *reinterpret_cast<const float4*>(W + lane * DD + j);
        Wp[j / 2 + 0] = v2f{w4.x, w4.y};
        Wp[j / 2 + 1] = v2f{w4.z, w4.w};
    }
#pragma unroll
    for (int p = 0; p < 32; ++p)
        asm("" : "+v"(Wp[p]));

    const float bi = bvec[lane];
    float x = x0[batch * DD + lane];
    float* outp = out + (size_t)batch * T_STEPS * DD + lane;

    float4* sA = &sbuf[0][0];
    float4* sB = &sbuf[1][0];

    for (int t = 0; t < T_STEPS; ++t) {
        // Trajectory stores the state BEFORE the update (off critical path).
        outp[(size_t)t * DD] = x;

        // term 1: z = Wx + b gives the regime mask
        const float z = matvec64(Wp, x, sA, lane) + bi;
        const float m_dt = (z > 0.f) ? DT_F : 0.f;
        float w = m_dt * z - DT_F * x;
        float y = x + w;

        // term 2
        {
            const float v = matvec64(Wp, w, sB, lane);
            w = (m_dt * v - DT_F * w) * 0.5f;
            y += w;
        }
        // term 3
        {
            const float v = matvec64(Wp, w, sA, lane);
            w = (m_dt * v - DT_F * w) * (1.0f / 3.0f);
            y += w;
        }
        x = y;
        // Swap so consecutive matvecs never reuse a slot back-to-back.
        float4* tmp = sA; sA = sB; sB = tmp;
    }
}

extern "C" void kernel_launch(void* const* d_in, const int* in_sizes, int n_in,
                              void* d_out, int out_size, void* d_ws, size_t ws_size,
                              hipStream_t stream) {
    const float* x0 = (const float*)d_in[0];   // (256, 64) f32
    const float* W  = (const float*)d_in[1];   // (64, 64)  f32
    const float* b  = (const float*)d_in[2];   // (64,)     f32
    float* out = (float*)d_out;                // (256, 100, 64) f32

    const int batch = in_sizes[0] / DD;        // 256
    abla_kernel<<<batch, DD, 0, stream>>>(x0, W, b, out);
}

// Round 7
// 120.197 us; speedup vs baseline: 1.1969x; 1.1969x over previous
//
#include <hip/hip_runtime.h>

// AnalyticalBoundedLineAttractor — exact linear-regime stepping via Taylor
// recurrence:
//   z = Wx + b; m_dt = (z>0)?dt:0
//   w1 = m_dt*z - dt*x;  wk = (m_dt*(W w) - dt*w)/k;  x+ = x + sum wk
// K=3 terms; measured absmax 0.0156 vs threshold 7.7e-2.
//
// R3-R6 post-mortem: VGPR_Count=48 in every round that loaded W rows
// directly from global — the compiler SINKS const-__restrict__ global loads
// into the matvec loop (L1-hot refetch, invisible in FETCH_SIZE), so every
// matvec paid ~16 hidden global_load_dwordx4 + vmcnt waits. R2 (W staged
// via LDS) reported 84 VGPRs = resident. This round: R3's readlane matvec
// UNCHANGED, but W goes global -> LDS (coalesced, once) -> VGPR (once).
// Clean A/B vs R3: only the W load path differs.

#define DT_F 0.05f
#define T_STEPS 100
#define DD 64
#define KT 3  // Taylor terms w_1..w_KT

__device__ __forceinline__ float matvec64(const float (&Wr)[DD], float w) {
    const int wi = __float_as_int(w);
    float a0 = 0.f, a1 = 0.f, a2 = 0.f, a3 = 0.f;
#pragma unroll
    for (int j = 0; j < DD; j += 4) {
        const float s0 = __int_as_float(__builtin_amdgcn_readlane(wi, j + 0));
        const float s1 = __int_as_float(__builtin_amdgcn_readlane(wi, j + 1));
        const float s2 = __int_as_float(__builtin_amdgcn_readlane(wi, j + 2));
        const float s3 = __int_as_float(__builtin_amdgcn_readlane(wi, j + 3));
        a0 = fmaf(Wr[j + 0], s0, a0);
        a1 = fmaf(Wr[j + 1], s1, a1);
        a2 = fmaf(Wr[j + 2], s2, a2);
        a3 = fmaf(Wr[j + 3], s3, a3);
    }
    return (a0 + a1) + (a2 + a3);
}

__global__ __launch_bounds__(64, 1)
void abla_kernel(const float* __restrict__ x0,
                 const float* __restrict__ W,
                 const float* __restrict__ bvec,
                 float* __restrict__ out) {
    const int batch = blockIdx.x;
    const int lane = threadIdx.x;

    // Stage W into LDS coalesced (one-time), then pull row `lane` into 64
    // VGPRs. LDS-sourced loads are NOT sunk into the loop by the compiler
    // (R2 evidence: VGPR_Count=84 with this path vs 48 with global loads).
    __shared__ float sW[DD * DD];
    for (int idx = lane; idx < DD * DD; idx += DD) sW[idx] = W[idx];
    __syncthreads();

    float Wr[DD];
#pragma unroll
    for (int j = 0; j < DD; j += 4) {
        const float4 w4 = *reinterpret_cast<const float4*>(sW + lane * DD + j);
        Wr[j + 0] = w4.x; Wr[j + 1] = w4.y; Wr[j + 2] = w4.z; Wr[j + 3] = w4.w;
    }

    const float bi = bvec[lane];
    float x = x0[batch * DD + lane];
    float* outp = out + (size_t)batch * T_STEPS * DD + lane;

    for (int t = 0; t < T_STEPS; ++t) {
        // Trajectory stores the state BEFORE the update (off critical path).
        outp[(size_t)t * DD] = x;

        // term 1: z = Wx + b gives the regime mask
        const float z = matvec64(Wr, x) + bi;
        const float m_dt = (z > 0.f) ? DT_F : 0.f;
        float w = m_dt * z - DT_F * x;
        float y = x + w;

        // terms 2..KT
#pragma unroll
        for (int k = 2; k <= KT; ++k) {
            const float v = matvec64(Wr, w);
            w = (m_dt * v - DT_F * w) * (1.0f / (float)k);
            y += w;
        }
        x = y;
    }
}

extern "C" void kernel_launch(void* const* d_in, const int* in_sizes, int n_in,
                              void* d_out, int out_size, void* d_ws, size_t ws_size,
                              hipStream_t stream) {
    const float* x0 = (const float*)d_in[0];   // (256, 64) f32
    const float* W  = (const float*)d_in[1];   // (64, 64)  f32
    const float* b  = (const float*)d_in[2];   // (64,)     f32
    float* out = (float*)d_out;                // (256, 100, 64) f32

    const int batch = in_sizes[0] / DD;        // 256
    abla_kernel<<<batch, DD, 0, stream>>>(x0, W, b, out);
}

// Round 8
// 120.106 us; speedup vs baseline: 1.1978x; 1.0008x over previous
//
#include <hip/hip_runtime.h>

// AnalyticalBoundedLineAttractor — exact linear-regime stepping via Taylor
// recurrence:
//   z = Wx + b; m_dt = (z>0)?dt:0
//   w1 = m_dt*z - dt*x;  wk = (m_dt*(W w) - dt*w)/k;  x+ = x + sum wk
// K=3 terms; measured absmax 0.0156 vs threshold 7.7e-2.
//
// R7 post-mortem: VGPR_Count=68 — still short of the ~85 needed for a fully
// resident W row, so the compiler re-read the tail of W from LDS inside the
// loop (~190 dynamic instr/matvec vs 128 in source). Fixes:
//  (a) asm "+v" pins on ALL W values INSIDE the t-loop (R5 pinned only
//      outside it) — W must be live-in-VGPR every iteration, so the
//      allocator has to keep it resident (~110 VGPRs).
//  (b) dual-pipe broadcast: j=0..31 via v_readlane+v_fmac (VALU), j=32..63
//      via ds_write + 8 broadcast ds_read_b128 (LDS pipe, issued FIRST so
//      its ~130-cyc latency hides under the readlane half) consumed with
//      v_pk_fma_f32. ~80 VALU instr/matvec, DS stream overlapped.

#define DT_F 0.05f
#define T_STEPS 100
#define DD 64
#define KT 3  // Taylor terms w_1..w_KT

typedef float v2f __attribute__((ext_vector_type(2)));

__device__ __forceinline__ float matvec64(const float (&Wlo)[32],
                                          const v2f (&Whi)[16],
                                          float w, float* __restrict__ sb,
                                          int lane) {
    // ---- LDS pipe first: stage w, issue all upper-half broadcast reads ----
    // Single wave: DS pipe is in-order (validated R5/R6), no barrier needed.
    // Wave-uniform addresses -> pure broadcast, conflict-free.
    sb[lane] = w;
    const float4* s4 = reinterpret_cast<const float4*>(sb);
    float4 q[8];
#pragma unroll
    for (int r = 0; r < 8; ++r) q[r] = s4[8 + r];  // j = 32 + 4r

    // ---- VALU pipe meanwhile: lower half via readlane broadcast ----
    const int wi = __float_as_int(w);
    float a0 = 0.f, a1 = 0.f, a2 = 0.f, a3 = 0.f;
#pragma unroll
    for (int j = 0; j < 32; j += 4) {
        const float s0 = __int_as_float(__builtin_amdgcn_readlane(wi, j + 0));
        const float s1 = __int_as_float(__builtin_amdgcn_readlane(wi, j + 1));
        const float s2 = __int_as_float(__builtin_amdgcn_readlane(wi, j + 2));
        const float s3 = __int_as_float(__builtin_amdgcn_readlane(wi, j + 3));
        a0 = fmaf(Wlo[j + 0], s0, a0);
        a1 = fmaf(Wlo[j + 1], s1, a1);
        a2 = fmaf(Wlo[j + 2], s2, a2);
        a3 = fmaf(Wlo[j + 3], s3, a3);
    }

    // ---- upper half: packed FMAs on the LDS broadcast values ----
    v2f p0 = {0.f, 0.f}, p1 = {0.f, 0.f};
#pragma unroll
    for (int r = 0; r < 8; ++r) {
        const v2f sa = {q[r].x, q[r].y};
        const v2f sc = {q[r].z, q[r].w};
        p0 = __builtin_elementwise_fma(Whi[2 * r + 0], sa, p0);
        p1 = __builtin_elementwise_fma(Whi[2 * r + 1], sc, p1);
    }
    const v2f ps = p0 + p1;
    return ((a0 + a1) + (a2 + a3)) + (ps.x + ps.y);
}

__global__ __launch_bounds__(64, 1)
void abla_kernel(const float* __restrict__ x0,
                 const float* __restrict__ W,
                 const float* __restrict__ bvec,
                 float* __restrict__ out) {
    const int batch = blockIdx.x;
    const int lane = threadIdx.x;

    __shared__ float sW[DD * DD];
    __shared__ float sbuf[2][DD];

    // Stage W coalesced into LDS (one-time), then pull row `lane` into VGPRs.
    for (int idx = lane; idx < DD * DD; idx += DD) sW[idx] = W[idx];
    __syncthreads();

    float Wlo[32];   // j = 0..31 (scalar fma operands)
    v2f Whi[16];     // j = 32..63 as pairs (pk_fma operands)
#pragma unroll
    for (int j = 0; j < 32; j += 4) {
        const float4 w4 = *reinterpret_cast<const float4*>(sW + lane * DD + j);
        Wlo[j + 0] = w4.x; Wlo[j + 1] = w4.y; Wlo[j + 2] = w4.z; Wlo[j + 3] = w4.w;
    }
#pragma unroll
    for (int j = 0; j < 32; j += 4) {
        const float4 w4 = *reinterpret_cast<const float4*>(sW + lane * DD + 32 + j);
        Whi[j / 2 + 0] = v2f{w4.x, w4.y};
        Whi[j / 2 + 1] = v2f{w4.z, w4.w};
    }

    const float bi = bvec[lane];
    float x = x0[batch * DD + lane];
    float* outp = out + (size_t)batch * T_STEPS * DD + lane;

    float* sA = &sbuf[0][0];
    float* sB = &sbuf[1][0];

    for (int t = 0; t < T_STEPS; ++t) {
        // In-loop residency pins: every W value must be live in a VGPR here,
        // each iteration — the allocator can no longer keep W in LDS/L1 and
        // refetch per matvec (R3-R7: VGPR_Count 48-68, ~60 hidden
        // W-supply instr/matvec).
        asm("" : "+v"(Wlo[0]), "+v"(Wlo[1]), "+v"(Wlo[2]), "+v"(Wlo[3]),
                 "+v"(Wlo[4]), "+v"(Wlo[5]), "+v"(Wlo[6]), "+v"(Wlo[7]));
        asm("" : "+v"(Wlo[8]), "+v"(Wlo[9]), "+v"(Wlo[10]), "+v"(Wlo[11]),
                 "+v"(Wlo[12]), "+v"(Wlo[13]), "+v"(Wlo[14]), "+v"(Wlo[15]));
        asm("" : "+v"(Wlo[16]), "+v"(Wlo[17]), "+v"(Wlo[18]), "+v"(Wlo[19]),
                 "+v"(Wlo[20]), "+v"(Wlo[21]), "+v"(Wlo[22]), "+v"(Wlo[23]));
        asm("" : "+v"(Wlo[24]), "+v"(Wlo[25]), "+v"(Wlo[26]), "+v"(Wlo[27]),
                 "+v"(Wlo[28]), "+v"(Wlo[29]), "+v"(Wlo[30]), "+v"(Wlo[31]));
        asm("" : "+v"(Whi[0]), "+v"(Whi[1]), "+v"(Whi[2]), "+v"(Whi[3]),
                 "+v"(Whi[4]), "+v"(Whi[5]), "+v"(Whi[6]), "+v"(Whi[7]));
        asm("" : "+v"(Whi[8]), "+v"(Whi[9]), "+v"(Whi[10]), "+v"(Whi[11]),
                 "+v"(Whi[12]), "+v"(Whi[13]), "+v"(Whi[14]), "+v"(Whi[15]));

        // Trajectory stores the state BEFORE the update (off critical path).
        outp[(size_t)t * DD] = x;

        // term 1: z = Wx + b gives the regime mask
        const float z = matvec64(Wlo, Whi, x, sA, lane) + bi;
        const float m_dt = (z > 0.f) ? DT_F : 0.f;
        float w = m_dt * z - DT_F * x;
        float y = x + w;

        // term 2
        {
            const float v = matvec64(Wlo, Whi, w, sB, lane);
            w = (m_dt * v - DT_F * w) * 0.5f;
            y += w;
        }
        // term 3
        {
            const float v = matvec64(Wlo, Whi, w, sA, lane);
            w = (m_dt * v - DT_F * w) * (1.0f / 3.0f);
            y += w;
        }
        x = y;
        float* tmp = sA; sA = sB; sB = tmp;
    }
}

extern "C" void kernel_launch(void* const* d_in, const int* in_sizes, int n_in,
                              void* d_out, int out_size, void* d_ws, size_t ws_size,
                              hipStream_t stream) {
    const float* x0 = (const float*)d_in[0];   // (256, 64) f32
    const float* W  = (const float*)d_in[1];   // (64, 64)  f32
    const float* b  = (const float*)d_in[2];   // (64,)     f32
    float* out = (float*)d_out;                // (256, 100, 64) f32

    const int batch = in_sizes[0] / DD;        // 256
    abla_kernel<<<batch, DD, 0, stream>>>(x0, W, b, out);
}